// Round 5
// baseline (7713.643 us; speedup 1.0000x reference)
//
#include <hip/hip_runtime.h>

#define DEV static __device__ __forceinline__

DEV float sigf(float x) { return 1.0f / (1.0f + __expf(-x)); }
DEV float ftanh(float x) {
  float xc = fminf(fmaxf(x, -9.0f), 9.0f);
  float e = __expf(2.0f * xc);
  return (e - 1.0f) / (e + 1.0f);
}

// ---------------- generic tiled f32 GEMM (NT): out[m][n] = sum_k A[m][k]*B[n][k] + bias[n]
__global__ __launch_bounds__(256) void gemm_nt_bias(
    const float* __restrict__ A, const float* __restrict__ B,
    const float* __restrict__ bias, float* __restrict__ out,
    int M, int N, int K)
{
  __shared__ float As[64][17];
  __shared__ float Bs[64][17];
  const int tid = threadIdx.x;
  const int m0 = blockIdx.y * 64, n0 = blockIdx.x * 64;
  const int lr = tid >> 2;
  const int lk = (tid & 3) << 2;
  const int ty = tid >> 4, tx = tid & 15;
  float acc[4][4] = {};
  for (int k0 = 0; k0 < K; k0 += 16) {
    float4 a4 = *(const float4*)(A + (size_t)(m0 + lr) * K + k0 + lk);
    float4 b4 = *(const float4*)(B + (size_t)(n0 + lr) * K + k0 + lk);
    As[lr][lk] = a4.x; As[lr][lk + 1] = a4.y; As[lr][lk + 2] = a4.z; As[lr][lk + 3] = a4.w;
    Bs[lr][lk] = b4.x; Bs[lr][lk + 1] = b4.y; Bs[lr][lk + 2] = b4.z; Bs[lr][lk + 3] = b4.w;
    __syncthreads();
#pragma unroll
    for (int kk = 0; kk < 16; ++kk) {
      float av[4], bv[4];
#pragma unroll
      for (int r = 0; r < 4; ++r) av[r] = As[ty * 4 + r][kk];
#pragma unroll
      for (int c = 0; c < 4; ++c) bv[c] = Bs[tx * 4 + c][kk];
#pragma unroll
      for (int r = 0; r < 4; ++r)
#pragma unroll
        for (int c = 0; c < 4; ++c) acc[r][c] = fmaf(av[r], bv[c], acc[r][c]);
    }
    __syncthreads();
  }
#pragma unroll
  for (int r = 0; r < 4; ++r) {
    int m = m0 + ty * 4 + r;
#pragma unroll
    for (int c = 0; c < 4; ++c) {
      int n = n0 + tx * 4 + c;
      out[(size_t)m * N + n] = acc[r][c] + bias[n];
    }
  }
}

// ---------------- init: transpose init_h AND zero the barrier flags (blocks 0..15 transpose, 16 zeros)
__global__ void init_k(const float* __restrict__ src, float* __restrict__ dstT,
                       int* __restrict__ flags)
{
  if (blockIdx.x == 16) {
    if (threadIdx.x < 128) flags[threadIdx.x] = 0;
    return;
  }
  int idx = blockIdx.x * 256 + threadIdx.x;
  int k4 = idx >> 5, b = idx & 31;
  ((float4*)dstT)[idx] = ((const float4*)src)[b * 128 + k4];
}

struct P {
  const float* xt;       // [32][2048] for this step
  const float* cprev;    // [32][512]
  const float* ym;       // [32]
  const float* pctx;     // [128][32][1024]
  const float* context;  // [128][32][1024]
  const float* x_mask;   // [128][32]
  const float* U;        // [2048][512]
  const float* Wcomb;    // [1024][512]
  const float* U_att;    // [1024]
  const float* Ux;       // [2048][512]
  const float* Wx;       // [2048][1024]
  const float* bx;       // [2048]
  float* hT;             // [128 k4][32 b] float4 (read P1, written P5)
  float* h1; float* h1T; float* c1;
  float* hproj;          // [32][1024]
  float* evals;          // [128][32]
  float* attT;           // [256 c4][32 b] float4
  float* hs_t; float* cs_t; float* atts_t;
  int* flags;            // 4 ints for this step
};

// all-resident grid barrier: release(threadfence) + count; poll; acquire(threadfence)
DEV void gbar(int* f)
{
  __syncthreads();
  if (threadIdx.x == 0) {
    __threadfence();                 // release: push this XCD's dirty lines to L3
    atomicAdd(f, 1);                 // device-scope
    while (__hip_atomic_load(f, __ATOMIC_RELAXED, __HIP_MEMORY_SCOPE_AGENT) < 512)
      __builtin_amdgcn_s_sleep(2);
    __threadfence();                 // acquire: invalidate stale L1/L2 lines
  }
  __syncthreads();
}

// One decode step: 512 blocks x 256 threads, MUST be exactly 2 blocks/CU resident.
__global__ __launch_bounds__(256, 2) void step_fused(P p)
{
  const int bid = blockIdx.x;
  const int tid = threadIdx.x;
  __shared__ float lds[512];

  // ---- P1: lstm1. block = one j; slots = gate(2b)|khalf(1b), b = tid&31.
  {
    const int b = tid & 31;
    const int slot = tid >> 5;
    const int kh = slot & 1;
    const int gate = slot >> 1;      // 0:i 1:f 2:o 3:g
    const int j = bid;
    const float* urow = p.U + (size_t)(gate * 512 + j) * 512 + kh * 256;
    const float4* h4p = (const float4*)p.hT + kh * 64 * 32;
    float acc = 0.f;
#pragma unroll 8
    for (int k4 = 0; k4 < 64; ++k4) {
      float4 h4 = h4p[k4 * 32 + b];
      float4 u4 = *(const float4*)(urow + k4 * 4);
      acc = fmaf(h4.x, u4.x, fmaf(h4.y, u4.y, fmaf(h4.z, u4.z, fmaf(h4.w, u4.w, acc))));
    }
    lds[slot * 32 + b] = acc;
    __syncthreads();
    if (tid < 32) {
      const int b2 = tid;
      float pi = p.xt[b2 * 2048 + j]        + lds[b2]        + lds[32 + b2];
      float pf = p.xt[b2 * 2048 + 512 + j]  + lds[64 + b2]   + lds[96 + b2];
      float po = p.xt[b2 * 2048 + 1024 + j] + lds[128 + b2]  + lds[160 + b2];
      float pg = p.xt[b2 * 2048 + 1536 + j] + lds[192 + b2]  + lds[224 + b2];
      float cold = p.cprev[b2 * 512 + j];
      float cn = sigf(pf) * cold + sigf(pi) * tanhf(pg);
      float hn = sigf(po) * tanhf(cn);
      float ymv = p.ym[b2];
      float hfall = p.hT[(j >> 2) * 128 + b2 * 4 + (j & 3)];
      float hm = ymv * hn + (1.f - ymv) * hfall;
      p.h1[b2 * 512 + j] = hm;
      p.h1T[(j >> 2) * 128 + b2 * 4 + (j & 3)] = hm;
      p.c1[b2 * 512 + j] = cn;   // unmasked, matches reference
    }
  }
  gbar(p.flags + 0);

  // ---- P2: hproj. block = 2 d's, split-K x4.
  {
    const int b = tid & 31;
    const int dl = (tid >> 5) & 1;
    const int kq = tid >> 6;
    const int d = bid * 2 + dl;
    const float* wrow = p.Wcomb + (size_t)d * 512 + kq * 128;
    const float4* h4p = (const float4*)p.h1T + kq * 32 * 32;
    float acc = 0.f;
#pragma unroll 8
    for (int k4 = 0; k4 < 32; ++k4) {
      float4 h4 = h4p[k4 * 32 + b];
      float4 w4 = *(const float4*)(wrow + k4 * 4);
      acc = fmaf(h4.x, w4.x, fmaf(h4.y, w4.y, fmaf(h4.z, w4.z, fmaf(h4.w, w4.w, acc))));
    }
    lds[tid] = acc;            // tid = kq*64 + dl*32 + b
    __syncthreads();
    if (tid < 64) {
      const int bb = tid & 31, dll = tid >> 5;
      float s = lds[dll * 32 + bb] + lds[64 + dll * 32 + bb]
              + lds[128 + dll * 32 + bb] + lds[192 + dll * 32 + bb];
      p.hproj[bb * 1024 + bid * 2 + dll] = s;
    }
  }
  gbar(p.flags + 1);

  // ---- P3: evals[t][b] = exp(xm * sum_c tanh(pctx+hproj)*U_att) * xm. 8 pairs/block.
  {
    const int s = tid >> 5, lane = tid & 31;
    const int pr = bid * 8 + s;          // 0..4095
    const int tx = pr >> 5, b = pr & 31;
    const float4* pc = (const float4*)(p.pctx + ((size_t)tx * 32 + b) * 1024);
    const float4* hp = (const float4*)(p.hproj + (size_t)b * 1024);
    const float4* ua = (const float4*)p.U_att;
    float acc = 0.f;
#pragma unroll
    for (int i = 0; i < 8; ++i) {
      int c4 = i * 32 + lane;
      float4 pv = pc[c4], hv = hp[c4], uv = ua[c4];
      acc += ftanh(pv.x + hv.x) * uv.x + ftanh(pv.y + hv.y) * uv.y
           + ftanh(pv.z + hv.z) * uv.z + ftanh(pv.w + hv.w) * uv.w;
    }
#pragma unroll
    for (int off = 16; off > 0; off >>= 1) acc += __shfl_down(acc, off, 32);
    if (lane == 0) {
      float xm = p.x_mask[tx * 32 + b];
      p.evals[tx * 32 + b] = __expf(acc * xm) * xm;
    }
  }
  gbar(p.flags + 2);

  // ---- P4: normalize + atted. block: b = bid>>4, c-chunk = bid&15 (64 c).
  {
    const int b = bid >> 4, cch = bid & 15;
    if (tid < 128) lds[tid] = p.evals[tid * 32 + b];
    __syncthreads();
    if (tid < 64) {
      float s = lds[tid] + lds[tid + 64];
#pragma unroll
      for (int off = 32; off > 0; off >>= 1) s += __shfl_down(s, off);
      if (tid == 0) lds[200] = s;
    }
    __syncthreads();
    const float inv = 1.0f / lds[200];
    const int cl = tid & 63, tq = tid >> 6;
    const int c = cch * 64 + cl;
    float acc = 0.f;
#pragma unroll 8
    for (int i = 0; i < 32; ++i) {
      int tt = tq * 32 + i;
      acc = fmaf(lds[tt], p.context[((size_t)tt * 32 + b) * 1024 + c], acc);
    }
    lds[256 + tid] = acc;     // tid = tq*64 + cl
    __syncthreads();
    if (tid < 64) {
      float tot = (lds[256 + tid] + lds[256 + 64 + tid]
                 + lds[256 + 128 + tid] + lds[256 + 192 + tid]) * inv;
      const int cc = cch * 64 + tid;
      p.atts_t[(size_t)b * 1024 + cc] = tot;
      p.attT[(cc >> 2) * 128 + b * 4 + (cc & 3)] = tot;
    }
  }
  gbar(p.flags + 3);

  // ---- P5: lstm2. block = one j.
  {
    const int b = tid & 31;
    const int slot = tid >> 5;
    const int kh = slot & 1;
    const int gate = slot >> 1;
    const int j = bid;
    const float* uxrow = p.Ux + (size_t)(gate * 512 + j) * 512 + kh * 256;
    const float* wxrow = p.Wx + (size_t)(gate * 512 + j) * 1024 + kh * 512;
    const float4* h4p = (const float4*)p.h1T + kh * 64 * 32;
    const float4* a4p = (const float4*)p.attT + kh * 128 * 32;
    float acc = 0.f;
#pragma unroll 8
    for (int k4 = 0; k4 < 64; ++k4) {
      float4 h4 = h4p[k4 * 32 + b];
      float4 u4 = *(const float4*)(uxrow + k4 * 4);
      acc = fmaf(h4.x, u4.x, fmaf(h4.y, u4.y, fmaf(h4.z, u4.z, fmaf(h4.w, u4.w, acc))));
    }
#pragma unroll 8
    for (int c4 = 0; c4 < 128; ++c4) {
      float4 v4 = a4p[c4 * 32 + b];
      float4 w4 = *(const float4*)(wxrow + c4 * 4);
      acc = fmaf(v4.x, w4.x, fmaf(v4.y, w4.y, fmaf(v4.z, w4.z, fmaf(v4.w, w4.w, acc))));
    }
    __syncthreads();   // lds reuse (P4 wrote it)
    lds[slot * 32 + b] = acc;
    __syncthreads();
    if (tid < 32) {
      const int b2 = tid;
      float pi = p.bx[j]        + lds[b2]       + lds[32 + b2];
      float pf = p.bx[512 + j]  + lds[64 + b2]  + lds[96 + b2];
      float po = p.bx[1024 + j] + lds[128 + b2] + lds[160 + b2];
      float pg = p.bx[1536 + j] + lds[192 + b2] + lds[224 + b2];
      float c1v = p.c1[b2 * 512 + j];
      float cn = sigf(pf) * c1v + sigf(pi) * tanhf(pg);
      float hn = sigf(po) * tanhf(cn);
      float ymv = p.ym[b2];
      float hf = p.h1[b2 * 512 + j];
      float hm = ymv * hn + (1.f - ymv) * hf;
      p.hs_t[b2 * 512 + j] = hm;
      p.cs_t[b2 * 512 + j] = cn;
      p.hT[(j >> 2) * 128 + b2 * 4 + (j & 3)] = hm;
    }
  }
}

extern "C" void kernel_launch(void* const* d_in, const int* in_sizes, int n_in,
                              void* d_out, int out_size, void* d_ws, size_t ws_size,
                              hipStream_t stream)
{
  const float* y_emb   = (const float*)d_in[0];
  const float* context = (const float*)d_in[1];
  const float* init_h  = (const float*)d_in[2];
  const float* init_c  = (const float*)d_in[3];
  const float* x_mask  = (const float*)d_in[4];
  const float* y_mask  = (const float*)d_in[5];
  const float* W       = (const float*)d_in[6];
  const float* U       = (const float*)d_in[7];
  const float* bvec    = (const float*)d_in[8];
  const float* Wx      = (const float*)d_in[9];
  const float* Ux      = (const float*)d_in[10];
  const float* bx      = (const float*)d_in[11];
  const float* Wc      = (const float*)d_in[12];
  const float* b_att   = (const float*)d_in[13];
  const float* Wcomb   = (const float*)d_in[14];
  const float* U_att   = (const float*)d_in[15];

  float* out  = (float*)d_out;
  float* hs   = out;
  float* cs   = out + (size_t)32 * 32 * 512;
  float* atts = out + (size_t)2 * 32 * 32 * 512;

  float* ws    = (float*)d_ws;
  float* pctx  = ws;
  float* x     = pctx + 4194304;
  float* h1    = x + 2097152;
  float* c1    = h1 + 16384;
  float* hproj = c1 + 16384;
  float* evals = hproj + 32768;
  float* hT    = evals + 4096;
  float* h1T   = hT + 16384;
  float* attT  = h1T + 16384;
  int*   flags = (int*)(attT + 32768);   // 128 ints

  gemm_nt_bias<<<dim3(16, 64), 256, 0, stream>>>(context, Wc, b_att, pctx, 4096, 1024, 1024);
  gemm_nt_bias<<<dim3(32, 16), 256, 0, stream>>>(y_emb, W, bvec, x, 1024, 2048, 256);
  init_k<<<17, 256, 0, stream>>>(init_h, hT, flags);

  P p;
  p.pctx = pctx; p.context = context; p.x_mask = x_mask;
  p.U = U; p.Wcomb = Wcomb; p.U_att = U_att;
  p.Ux = Ux; p.Wx = Wx; p.bx = bx;
  p.hT = hT; p.h1 = h1; p.h1T = h1T; p.c1 = c1;
  p.hproj = hproj; p.evals = evals; p.attT = attT;

  for (int t = 0; t < 32; ++t) {
    p.xt     = x + (size_t)t * 65536;
    p.cprev  = t ? cs + (size_t)(t - 1) * 16384 : init_c;
    p.ym     = y_mask + t * 32;
    p.hs_t   = hs + (size_t)t * 16384;
    p.cs_t   = cs + (size_t)t * 16384;
    p.atts_t = atts + (size_t)t * 32768;
    p.flags  = flags + t * 4;
    step_fused<<<512, 256, 0, stream>>>(p);
  }
}

// Round 6
// 3177.373 us; speedup vs baseline: 2.4277x; 2.4277x over previous
//
#include <hip/hip_runtime.h>

#define DEV static __device__ __forceinline__

DEV float sigf(float x) { return 1.0f / (1.0f + __expf(-x)); }
DEV float ftanh(float x) {
  float xc = fminf(fmaxf(x, -9.0f), 9.0f);
  float e = __expf(2.0f * xc);
  return (e - 1.0f) / (e + 1.0f);
}

// ---------------- generic tiled f32 GEMM (NT): out[m][n] = sum_k A[m][k]*B[n][k] + bias[n]
__global__ __launch_bounds__(256) void gemm_nt_bias(
    const float* __restrict__ A, const float* __restrict__ B,
    const float* __restrict__ bias, float* __restrict__ out,
    int M, int N, int K)
{
  __shared__ float As[64][17];
  __shared__ float Bs[64][17];
  const int tid = threadIdx.x;
  const int m0 = blockIdx.y * 64, n0 = blockIdx.x * 64;
  const int lr = tid >> 2;
  const int lk = (tid & 3) << 2;
  const int ty = tid >> 4, tx = tid & 15;
  float acc[4][4] = {};
  for (int k0 = 0; k0 < K; k0 += 16) {
    float4 a4 = *(const float4*)(A + (size_t)(m0 + lr) * K + k0 + lk);
    float4 b4 = *(const float4*)(B + (size_t)(n0 + lr) * K + k0 + lk);
    As[lr][lk] = a4.x; As[lr][lk + 1] = a4.y; As[lr][lk + 2] = a4.z; As[lr][lk + 3] = a4.w;
    Bs[lr][lk] = b4.x; Bs[lr][lk + 1] = b4.y; Bs[lr][lk + 2] = b4.z; Bs[lr][lk + 3] = b4.w;
    __syncthreads();
#pragma unroll
    for (int kk = 0; kk < 16; ++kk) {
      float av[4], bv[4];
#pragma unroll
      for (int r = 0; r < 4; ++r) av[r] = As[ty * 4 + r][kk];
#pragma unroll
      for (int c = 0; c < 4; ++c) bv[c] = Bs[tx * 4 + c][kk];
#pragma unroll
      for (int r = 0; r < 4; ++r)
#pragma unroll
        for (int c = 0; c < 4; ++c) acc[r][c] = fmaf(av[r], bv[c], acc[r][c]);
    }
    __syncthreads();
  }
#pragma unroll
  for (int r = 0; r < 4; ++r) {
    int m = m0 + ty * 4 + r;
#pragma unroll
    for (int c = 0; c < 4; ++c) {
      int n = n0 + tx * 4 + c;
      out[(size_t)m * N + n] = acc[r][c] + bias[n];
    }
  }
}

__global__ void transpose_h(const float* __restrict__ src /*[32][512]*/,
                            float* __restrict__ dstT /*[128][32] float4*/)
{
  int idx = blockIdx.x * 256 + threadIdx.x;
  if (idx < 4096) {
    int k4 = idx >> 5, b = idx & 31;
    ((float4*)dstT)[idx] = ((const float4*)src)[b * 128 + k4];
  }
}

// ---------------- K1: lstm1, 512 blocks (one j each), slots = gate(2b)|khalf(1b)
__global__ __launch_bounds__(256) void lstm1_k(
    const float* __restrict__ xt, const float* __restrict__ hT,
    const float* __restrict__ cprev, const float* __restrict__ U,
    const float* __restrict__ ym,
    float* __restrict__ h1, float* __restrict__ h1T, float* __restrict__ c1)
{
  const int tid = threadIdx.x;
  const int b = tid & 31;
  const int slot = tid >> 5;     // 0..7
  const int kh = slot & 1;
  const int gate = slot >> 1;    // 0:i 1:f 2:o 3:g
  const int j = blockIdx.x;      // 0..511
  const float* urow = U + (size_t)(gate * 512 + j) * 512 + kh * 256;
  const float4* h4p = (const float4*)hT + kh * 64 * 32;
  float acc = 0.f;
#pragma unroll 8
  for (int k4 = 0; k4 < 64; ++k4) {
    float4 h4 = h4p[k4 * 32 + b];
    float4 u4 = *(const float4*)(urow + k4 * 4);
    acc = fmaf(h4.x, u4.x, fmaf(h4.y, u4.y, fmaf(h4.z, u4.z, fmaf(h4.w, u4.w, acc))));
  }
  __shared__ float lds[256];
  lds[slot * 32 + b] = acc;
  __syncthreads();
  if (tid < 32) {
    const int b2 = tid;
    float pi = xt[b2 * 2048 + j]        + lds[b2]        + lds[32 + b2];
    float pf = xt[b2 * 2048 + 512 + j]  + lds[64 + b2]   + lds[96 + b2];
    float po = xt[b2 * 2048 + 1024 + j] + lds[128 + b2]  + lds[160 + b2];
    float pg = xt[b2 * 2048 + 1536 + j] + lds[192 + b2]  + lds[224 + b2];
    float cold = cprev[b2 * 512 + j];
    float cn = sigf(pf) * cold + sigf(pi) * tanhf(pg);
    float hn = sigf(po) * tanhf(cn);
    float ymv = ym[b2];
    float hfall = hT[(j >> 2) * 128 + b2 * 4 + (j & 3)];
    float hm = ymv * hn + (1.f - ymv) * hfall;
    h1[b2 * 512 + j] = hm;
    h1T[(j >> 2) * 128 + b2 * 4 + (j & 3)] = hm;
    c1[b2 * 512 + j] = cn;   // unmasked, matches reference
  }
}

// ---------------- K2: fused attention for one batch row b.
// hproj (1024x512 matvec) -> score over 128 t (tanh dot) -> softmax -> atted.
// 32 blocks x 1024 threads.
__global__ __launch_bounds__(1024) void attn_k(
    const float* __restrict__ h1,      // [32][512]
    const float* __restrict__ Wcomb,   // [1024][512]
    const float* __restrict__ U_att,   // [1024]
    const float* __restrict__ x_mask,  // [128][32]
    const float* __restrict__ pctx,    // [128][32][1024]
    const float* __restrict__ context, // [128][32][1024]
    float* __restrict__ atts_t,        // [32][1024] slice of output
    float* __restrict__ attT)          // [256 c4][32 b] float4
{
  const int b = blockIdx.x;           // 0..31
  const int tid = threadIdx.x;        // 0..1023
  __shared__ float hsh[512];
  __shared__ float hp[1024];
  __shared__ float ev[128];
  __shared__ float invs;
  __shared__ float4 part[4][256];

  if (tid < 512) hsh[tid] = h1[b * 512 + tid];
  __syncthreads();

  // ---- hproj: half-wave (32 lanes) per c, coalesced Wcomb rows.
  {
    const int wv = tid >> 6;          // 0..15
    const int lane = tid & 63;
    const int hl = lane >> 5;         // 0..1
    const int kl = lane & 31;         // float4 slot
    const float4* hs4 = (const float4*)hsh;
    float4 h0 = hs4[kl], h1r = hs4[kl + 32], h2r = hs4[kl + 64], h3r = hs4[kl + 96];
    const float4* w4 = (const float4*)Wcomb;
#pragma unroll 4
    for (int i = 0; i < 32; ++i) {
      int c = wv * 64 + i * 2 + hl;
      const float4* wr = w4 + (size_t)c * 128;
      float4 w0 = wr[kl], w1 = wr[kl + 32], w2 = wr[kl + 64], w3 = wr[kl + 96];
      float acc = h0.x * w0.x + h0.y * w0.y + h0.z * w0.z + h0.w * w0.w;
      acc = fmaf(h1r.x, w1.x, fmaf(h1r.y, w1.y, fmaf(h1r.z, w1.z, fmaf(h1r.w, w1.w, acc))));
      acc = fmaf(h2r.x, w2.x, fmaf(h2r.y, w2.y, fmaf(h2r.z, w2.z, fmaf(h2r.w, w2.w, acc))));
      acc = fmaf(h3r.x, w3.x, fmaf(h3r.y, w3.y, fmaf(h3r.z, w3.z, fmaf(h3r.w, w3.w, acc))));
#pragma unroll
      for (int off = 16; off > 0; off >>= 1) acc += __shfl_down(acc, off, 32);
      if (kl == 0) hp[c] = acc;
    }
  }
  __syncthreads();

  // ---- score: thread = (t, c-chunk). t = tid>>3 (0..127), cc = tid&7 (128 c each).
  {
    const int t = tid >> 3, cc = tid & 7;
    const float4* pr = (const float4*)(pctx + ((size_t)t * 32 + b) * 1024) + cc * 32;
    const float4* hpp = (const float4*)hp + cc * 32;
    const float4* ua = (const float4*)U_att + cc * 32;
    float acc = 0.f;
#pragma unroll 8
    for (int i = 0; i < 32; ++i) {
      float4 pv = pr[i], hv = hpp[i], uv = ua[i];
      acc += ftanh(pv.x + hv.x) * uv.x + ftanh(pv.y + hv.y) * uv.y
           + ftanh(pv.z + hv.z) * uv.z + ftanh(pv.w + hv.w) * uv.w;
    }
    acc += __shfl_down(acc, 4, 8);
    acc += __shfl_down(acc, 2, 8);
    acc += __shfl_down(acc, 1, 8);
    if (cc == 0) {
      float xm = x_mask[t * 32 + b];
      ev[t] = __expf(acc * xm) * xm;   // max-subtract skipped: cancels in ratio
    }
  }
  __syncthreads();
  if (tid < 64) {
    float s = ev[tid] + ev[tid + 64];
#pragma unroll
    for (int off = 32; off > 0; off >>= 1) s += __shfl_down(s, off);
    if (tid == 0) invs = 1.0f / s;
  }
  __syncthreads();

  // ---- atted: c4 = tid&255 (float4 of c), tq = tid>>8 (quarter of t-range).
  {
    const int c4 = tid & 255, tq = tid >> 8;
    const float4* ctx4 = (const float4*)context;
    float4 acc = make_float4(0.f, 0.f, 0.f, 0.f);
#pragma unroll 8
    for (int i = 0; i < 32; ++i) {
      int t = tq * 32 + i;
      float a = ev[t];
      float4 v = ctx4[((size_t)t * 32 + b) * 256 + c4];
      acc.x = fmaf(a, v.x, acc.x); acc.y = fmaf(a, v.y, acc.y);
      acc.z = fmaf(a, v.z, acc.z); acc.w = fmaf(a, v.w, acc.w);
    }
    part[tq][c4] = acc;
  }
  __syncthreads();
  if (tid < 256) {
    float4 p0 = part[0][tid], p1 = part[1][tid], p2 = part[2][tid], p3 = part[3][tid];
    float4 tot;
    const float inv = invs;
    tot.x = (p0.x + p1.x + p2.x + p3.x) * inv;
    tot.y = (p0.y + p1.y + p2.y + p3.y) * inv;
    tot.z = (p0.z + p1.z + p2.z + p3.z) * inv;
    tot.w = (p0.w + p1.w + p2.w + p3.w) * inv;
    ((float4*)(atts_t + (size_t)b * 1024))[tid] = tot;
    ((float4*)attT)[(size_t)tid * 32 + b] = tot;
  }
}

// ---------------- K3: lstm2, 512 blocks (one j each)
__global__ __launch_bounds__(256) void lstm2_k(
    const float* __restrict__ h1, const float* __restrict__ h1T,
    const float* __restrict__ c1, const float* __restrict__ attT,
    const float* __restrict__ Ux, const float* __restrict__ Wx,
    const float* __restrict__ bx, const float* __restrict__ ym,
    float* __restrict__ hs_t, float* __restrict__ cs_t,
    float* __restrict__ hT_next)
{
  const int tid = threadIdx.x;
  const int b = tid & 31;
  const int slot = tid >> 5;
  const int kh = slot & 1;
  const int gate = slot >> 1;
  const int j = blockIdx.x;
  const float* uxrow = Ux + (size_t)(gate * 512 + j) * 512 + kh * 256;
  const float* wxrow = Wx + (size_t)(gate * 512 + j) * 1024 + kh * 512;
  const float4* h4p = (const float4*)h1T + kh * 64 * 32;
  const float4* a4p = (const float4*)attT + kh * 128 * 32;
  float acc = 0.f;
#pragma unroll 8
  for (int k4 = 0; k4 < 64; ++k4) {
    float4 h4 = h4p[k4 * 32 + b];
    float4 u4 = *(const float4*)(uxrow + k4 * 4);
    acc = fmaf(h4.x, u4.x, fmaf(h4.y, u4.y, fmaf(h4.z, u4.z, fmaf(h4.w, u4.w, acc))));
  }
#pragma unroll 8
  for (int c4 = 0; c4 < 128; ++c4) {
    float4 v4 = a4p[c4 * 32 + b];
    float4 w4 = *(const float4*)(wxrow + c4 * 4);
    acc = fmaf(v4.x, w4.x, fmaf(v4.y, w4.y, fmaf(v4.z, w4.z, fmaf(v4.w, w4.w, acc))));
  }
  __shared__ float lds[256];
  lds[slot * 32 + b] = acc;
  __syncthreads();
  if (tid < 32) {
    const int b2 = tid;
    float pi = bx[j]        + lds[b2]       + lds[32 + b2];
    float pf = bx[512 + j]  + lds[64 + b2]  + lds[96 + b2];
    float po = bx[1024 + j] + lds[128 + b2] + lds[160 + b2];
    float pg = bx[1536 + j] + lds[192 + b2] + lds[224 + b2];
    float c1v = c1[b2 * 512 + j];
    float cn = sigf(pf) * c1v + sigf(pi) * tanhf(pg);
    float hn = sigf(po) * tanhf(cn);
    float ymv = ym[b2];
    float hf = h1[b2 * 512 + j];
    float hm = ymv * hn + (1.f - ymv) * hf;
    hs_t[b2 * 512 + j] = hm;
    cs_t[b2 * 512 + j] = cn;
    hT_next[(j >> 2) * 128 + b2 * 4 + (j & 3)] = hm;
  }
}

extern "C" void kernel_launch(void* const* d_in, const int* in_sizes, int n_in,
                              void* d_out, int out_size, void* d_ws, size_t ws_size,
                              hipStream_t stream)
{
  const float* y_emb   = (const float*)d_in[0];
  const float* context = (const float*)d_in[1];
  const float* init_h  = (const float*)d_in[2];
  const float* init_c  = (const float*)d_in[3];
  const float* x_mask  = (const float*)d_in[4];
  const float* y_mask  = (const float*)d_in[5];
  const float* W       = (const float*)d_in[6];
  const float* U       = (const float*)d_in[7];
  const float* bvec    = (const float*)d_in[8];
  const float* Wx      = (const float*)d_in[9];
  const float* Ux      = (const float*)d_in[10];
  const float* bx      = (const float*)d_in[11];
  const float* Wc      = (const float*)d_in[12];
  const float* b_att   = (const float*)d_in[13];
  const float* Wcomb   = (const float*)d_in[14];
  const float* U_att   = (const float*)d_in[15];

  float* out  = (float*)d_out;
  float* hs   = out;
  float* cs   = out + (size_t)32 * 32 * 512;
  float* atts = out + (size_t)2 * 32 * 32 * 512;

  float* ws    = (float*)d_ws;
  float* pctx  = ws;                 // 4194304
  float* x     = pctx + 4194304;     // 2097152
  float* h1    = x + 2097152;        // 16384
  float* c1    = h1 + 16384;         // 16384
  float* hT    = c1 + 16384;         // 16384
  float* h1T   = hT + 16384;         // 16384
  float* attT  = h1T + 16384;        // 32768

  gemm_nt_bias<<<dim3(16, 64), 256, 0, stream>>>(context, Wc, b_att, pctx, 4096, 1024, 1024);
  gemm_nt_bias<<<dim3(32, 16), 256, 0, stream>>>(y_emb, W, bvec, x, 1024, 2048, 256);
  transpose_h<<<16, 256, 0, stream>>>(init_h, hT);

  for (int t = 0; t < 32; ++t) {
    const float* cp = t ? cs + (size_t)(t - 1) * 16384 : init_c;
    lstm1_k<<<512, 256, 0, stream>>>(x + (size_t)t * 65536, hT, cp, U, y_mask + t * 32, h1, h1T, c1);
    attn_k<<<32, 1024, 0, stream>>>(h1, Wcomb, U_att, x_mask, pctx, context,
                                    atts + (size_t)t * 32768, attT);
    lstm2_k<<<512, 256, 0, stream>>>(h1, h1T, c1, attT, Ux, Wx, bx, y_mask + t * 32,
                                     hs + (size_t)t * 16384, cs + (size_t)t * 16384, hT);
  }
}